// Round 9
// baseline (232.367 us; speedup 1.0000x reference)
//
#include <hip/hip_runtime.h>

// GatedLTMMemory: 4096 rows, QD=320, D=512, S=1024, H=8, K=32, DH=64
// Dtype (fp32 vs bf16) derived inline from ln_g[0] (== 1.0). (Resolved: fp32.)

__device__ __forceinline__ float bf2f(unsigned short u) {
    return __uint_as_float(((unsigned int)u) << 16);
}
__device__ __forceinline__ unsigned short f2bf(float f) {
    unsigned int u = __float_as_uint(f);
    u += 0x7FFFu + ((u >> 16) & 1u);
    return (unsigned short)(u >> 16);
}
__device__ __forceinline__ int detect_bf(const void* g) {
    return ((*(const unsigned int*)g) & 0xFFFFu) != 0u;
}
__device__ __forceinline__ float ldg1(const void* p, size_t i, int bf) {
    return bf ? bf2f(((const unsigned short*)p)[i]) : ((const float*)p)[i];
}
__device__ __forceinline__ void ld4(const void* p, size_t i, int bf, float* o) {
    if (bf) {
        ushort4 v = *reinterpret_cast<const ushort4*>((const unsigned short*)p + i);
        o[0] = bf2f(v.x); o[1] = bf2f(v.y); o[2] = bf2f(v.z); o[3] = bf2f(v.w);
    } else {
        float4 v = *reinterpret_cast<const float4*>((const float*)p + i);
        o[0] = v.x; o[1] = v.y; o[2] = v.z; o[3] = v.w;
    }
}
__device__ __forceinline__ unsigned int fkey(float x) {
    unsigned int u = __float_as_uint(x);
    return (u & 0x80000000u) ? ~u : (u | 0x80000000u);
}
__device__ __forceinline__ float funkey(unsigned int k) {
    unsigned int u = (k & 0x80000000u) ? (k & 0x7FFFFFFFu) : ~k;
    return __uint_as_float(u);
}

typedef __attribute__((ext_vector_type(8))) short bf16x8;
typedef __attribute__((ext_vector_type(4))) float f32x4;
typedef __attribute__((ext_vector_type(4))) unsigned int u32x4;

// split 8 fp32 into hi/lo bf16 packs via v_cvt_pk_bf16_f32 (RNE):
// x ~= bf2f(hi) + bf2f(lo); residual ~2^-17|x| (captured by 4-pass).
__device__ __forceinline__ void split8(const float* x, u32x4& h, u32x4& l) {
#pragma unroll
    for (int j = 0; j < 4; j++) {
        float x0 = x[2 * j], x1 = x[2 * j + 1];
        unsigned int hp, lp;
        asm("v_cvt_pk_bf16_f32 %0, %1, %2" : "=v"(hp) : "v"(x0), "v"(x1));
        float h0 = __uint_as_float(hp << 16);
        float h1 = __uint_as_float(hp & 0xFFFF0000u);
        float l0 = x0 - h0, l1 = x1 - h1;
        asm("v_cvt_pk_bf16_f32 %0, %1, %2" : "=v"(lp) : "v"(l0), "v"(l1));
        h[j] = hp; l[j] = lp;
    }
}

// async global -> LDS, 16 bytes per lane. LDS dest = wave-uniform base +
// lane*16 (linear); per-lane global source (pre-swizzled by caller).
__device__ __forceinline__ void gload16(const void* g, void* l) {
    __builtin_amdgcn_global_load_lds(
        (const __attribute__((address_space(1))) unsigned int*)g,
        (__attribute__((address_space(3))) unsigned int*)l,
        16, 0, 0);
}

// ---------------------------------------------------------------------------
// Fused prep: blockIdx.x < 2048 -> norms; < 2208 -> WqpT transpose;
// else presplit X (640 blocks).
// ---------------------------------------------------------------------------
__global__ __launch_bounds__(256) void prep_fused(
    const void* __restrict__ keys, const void* __restrict__ vals,
    const void* __restrict__ Wqp, const void* __restrict__ X,
    const void* __restrict__ gdet,
    float* __restrict__ inv_kf, float* __restrict__ inv_vf,
    float* __restrict__ WqpT,
    unsigned short* __restrict__ Xh, unsigned short* __restrict__ Xl)
{
    __shared__ double red[256];
    __shared__ float tile[32][36];
    const int bf = detect_bf(gdet);
    const int bid = blockIdx.x, t = threadIdx.x;
    if (bid < 2048) {
        int r = bid;
        const void* src = (r < 1024) ? keys : vals;
        size_t base = (size_t)((r < 1024) ? r : r - 1024) * 512;
        float x0 = ldg1(src, base + t, bf), x1 = ldg1(src, base + t + 256, bf);
        red[t] = (double)x0 * x0 + (double)x1 * x1;
        __syncthreads();
        for (int s = 128; s > 0; s >>= 1) {
            if (t < s) red[t] += red[t + s];
            __syncthreads();
        }
        if (t == 0) {
            float rs = (float)(1.0 / sqrt(red[0] + 1e-12));
            if (r < 1024) inv_kf[r] = rs;
            else          inv_vf[r - 1024] = rs;
        }
    } else if (bid < 2208) {
        int tid = bid - 2048;                 // 160 blocks: 16 x 10
        int d0 = (tid & 15) * 32, q0 = (tid >> 4) * 32;
        int r = t >> 3, c = (t & 7) * 4;
        float v[4];
        ld4(Wqp, (size_t)(d0 + r) * 320 + q0 + c, bf, v);
#pragma unroll
        for (int i = 0; i < 4; i++) tile[r][c + i] = v[i];
        __syncthreads();
        float o[4];
#pragma unroll
        for (int i = 0; i < 4; i++) o[i] = tile[c + i][r];
        *reinterpret_cast<float4*>(&WqpT[(size_t)(q0 + r) * 512 + d0 + c]) =
            make_float4(o[0], o[1], o[2], o[3]);
    } else {
        int i = (bid - 2208) * 256 + t;       // 640 blocks x 256 = 163840
        float v[8];
        ld4(X, (size_t)i * 8, bf, v);
        ld4(X, (size_t)i * 8 + 4, bf, v + 4);
        u32x4 h, l;
        split8(v, h, l);
        *reinterpret_cast<u32x4*>(Xh + (size_t)i * 8) = h;
        *reinterpret_cast<u32x4*>(Xl + (size_t)i * 8) = l;
    }
}

// ---------------------------------------------------------------------------
// Unified split-MFMA ABT: C = rowop(A) @ B^T, K=512 fixed, bf16 split
// emulation. npass=3: Ah·Bh+Al·Bh+Ah·Bl (err ~3e-5). npass=4: +Al·Bl
// (fp32-GEMM-accurate). BM=32, BN=64, BK=64, 4 waves, wave=16x32.
// LDS 24 KB, XOR chunk swizzle. T14 prefetch after the 2nd barrier.
// amode 2 with stats==nullptr: compute LN stats in-kernel (pre-pass over A,
// fp64 accumulate + 8-lane shuffle reduce — ln_stats-equivalent).
// ---------------------------------------------------------------------------
__global__ __launch_bounds__(256) void mfma_abt(
    const void* __restrict__ A, const void* __restrict__ B,
    const float* __restrict__ scale, float* __restrict__ C,
    const void* __restrict__ A2, const void* __restrict__ B2,
    const float* __restrict__ scale2, float* __restrict__ C2, int ysplit,
    const float2* __restrict__ stats, const void* __restrict__ g,
    const void* __restrict__ bvec, const void* __restrict__ bias,
    void* __restrict__ O,
    unsigned short* __restrict__ Hout, unsigned short* __restrict__ Lout,
    int hrow0a, int hrow0b,
    int N, int amode, int abfon, int bbfon, int epi, int npass,
    const void* __restrict__ gdet)
{
    __shared__ __align__(16) short lds[12288];
    const int AHo = 0, ALo = 2048, BHo = 4096, BLo = 8192;  // short units
    const int flag = detect_bf(gdet);
    const int abf = abfon ? flag : 0;
    const int bbf = bbfon ? flag : 0;
    const int t = threadIdx.x;
    int by = blockIdx.y;
    const void* Ap = A; const void* Bp = B;
    const float* scp = scale; float* Cp = C;
    int hrow0 = hrow0a;
    if (ysplit && by >= ysplit) {
        Ap = A2; Bp = B2; scp = scale2; Cp = C2; by -= ysplit; hrow0 = hrow0b;
    }
    const int m0 = by * 32, n0 = blockIdx.x * 64;
    const int lane = t & 63, wv = t >> 6;
    const int wm = wv >> 1, wn = wv & 1;
    const int srow = t >> 3;   // 0..31
    const int sc8  = t & 7;    // chunk of 8 elements

    int aoff[2], boff[2][2];
#pragma unroll
    for (int kk = 0; kk < 2; kk++) {
        int ra = wm * 16 + (lane & 15);
        int ca = kk * 4 + (lane >> 4);
        aoff[kk] = ra * 64 + ((ca ^ (ra & 7)) << 3);
    }
#pragma unroll
    for (int ni = 0; ni < 2; ni++)
#pragma unroll
        for (int kk = 0; kk < 2; kk++) {
            int rb = wn * 32 + ni * 16 + (lane & 15);
            int cb = kk * 4 + (lane >> 4);
            boff[ni][kk] = rb * 64 + ((cb ^ (rb & 7)) << 3);
        }

    const int addr0 = srow * 64 + ((sc8 ^ (srow & 7)) << 3);
    const int addr1 = addr0 + 32 * 64;   // (srow+32)&7 == srow&7

    float s0 = 1.0f;
    float2 st0 = make_float2(0.f, 1.f);
    if (amode == 1) {
        s0 = scp ? scp[m0 + srow] : 1.0f;
    } else if (amode == 2) {
        if (stats) {
            st0 = stats[m0 + srow];
        } else {
            // inline LN stats: row srow covered by the 8 threads sc8=0..7
            double s = 0.0, ss = 0.0;
            for (int kb2 = 0; kb2 < 512; kb2 += 64) {
                float v8[8];
                ld4(Ap, (size_t)(m0 + srow) * 512 + kb2 + sc8 * 8,     abf, v8);
                ld4(Ap, (size_t)(m0 + srow) * 512 + kb2 + sc8 * 8 + 4, abf, v8 + 4);
#pragma unroll
                for (int j = 0; j < 8; j++) {
                    s  += (double)v8[j];
                    ss += (double)v8[j] * v8[j];
                }
            }
            s  += __shfl_xor(s, 1, 64);  ss += __shfl_xor(ss, 1, 64);
            s  += __shfl_xor(s, 2, 64);  ss += __shfl_xor(ss, 2, 64);
            s  += __shfl_xor(s, 4, 64);  ss += __shfl_xor(ss, 4, 64);
            double mu = s / 512.0, var = ss / 512.0 - mu * mu;
            st0 = make_float2((float)mu, (float)(1.0 / sqrt(var + 1e-5)));
        }
    }

    f32x4 acc[2];
    acc[0] = (f32x4){0.f, 0.f, 0.f, 0.f};
    acc[1] = (f32x4){0.f, 0.f, 0.f, 0.f};

    float av0[8], bv0[8], bv1[8];
    {
        ld4(Ap, (size_t)(m0 + srow) * 512 + sc8 * 8,          abf, av0);
        ld4(Ap, (size_t)(m0 + srow) * 512 + sc8 * 8 + 4,      abf, av0 + 4);
        ld4(Bp, (size_t)(n0 + srow) * 512 + sc8 * 8,          bbf, bv0);
        ld4(Bp, (size_t)(n0 + srow) * 512 + sc8 * 8 + 4,      bbf, bv0 + 4);
        ld4(Bp, (size_t)(n0 + srow + 32) * 512 + sc8 * 8,     bbf, bv1);
        ld4(Bp, (size_t)(n0 + srow + 32) * 512 + sc8 * 8 + 4, bbf, bv1 + 4);
    }

    for (int ks = 0; ks < 8; ks++) {
        const int kb = ks * 64;
        float a0[8], b0[8], b1[8];
#pragma unroll
        for (int j = 0; j < 8; j++) { a0[j] = av0[j]; b0[j] = bv0[j]; b1[j] = bv1[j]; }
        if (amode == 1) {
#pragma unroll
            for (int j = 0; j < 8; j++) a0[j] *= s0;
        } else if (amode == 2) {
            float gv[8], bv8[8];
            ld4(g,    (size_t)(kb + sc8 * 8),     flag, gv);
            ld4(g,    (size_t)(kb + sc8 * 8 + 4), flag, gv + 4);
            ld4(bvec, (size_t)(kb + sc8 * 8),     flag, bv8);
            ld4(bvec, (size_t)(kb + sc8 * 8 + 4), flag, bv8 + 4);
#pragma unroll
            for (int j = 0; j < 8; j++)
                a0[j] = (a0[j] - st0.x) * st0.y * gv[j] + bv8[j];
        }
        u32x4 ah0, al0, bh0, bl0, bh1, bl1;
        split8(a0, ah0, al0);
        split8(b0, bh0, bl0); split8(b1, bh1, bl1);
        __syncthreads();
        *reinterpret_cast<u32x4*>(&lds[AHo + addr0]) = ah0;
        *reinterpret_cast<u32x4*>(&lds[ALo + addr0]) = al0;
        *reinterpret_cast<u32x4*>(&lds[BHo + addr0]) = bh0;
        *reinterpret_cast<u32x4*>(&lds[BHo + addr1]) = bh1;
        *reinterpret_cast<u32x4*>(&lds[BLo + addr0]) = bl0;
        *reinterpret_cast<u32x4*>(&lds[BLo + addr1]) = bl1;
        __syncthreads();
        if (ks < 7) {
            const int kn = kb + 64;
            ld4(Ap, (size_t)(m0 + srow) * 512 + kn + sc8 * 8,          abf, av0);
            ld4(Ap, (size_t)(m0 + srow) * 512 + kn + sc8 * 8 + 4,      abf, av0 + 4);
            ld4(Bp, (size_t)(n0 + srow) * 512 + kn + sc8 * 8,          bbf, bv0);
            ld4(Bp, (size_t)(n0 + srow) * 512 + kn + sc8 * 8 + 4,      bbf, bv0 + 4);
            ld4(Bp, (size_t)(n0 + srow + 32) * 512 + kn + sc8 * 8,     bbf, bv1);
            ld4(Bp, (size_t)(n0 + srow + 32) * 512 + kn + sc8 * 8 + 4, bbf, bv1 + 4);
        }
        for (int p = 0; p < npass; p++) {
            const int Ab = (p == 1 || p == 3) ? ALo : AHo;
            const int Bb = (p >= 2) ? BLo : BHo;
#pragma unroll
            for (int kk = 0; kk < 2; kk++) {
                bf16x8 af, bfr[2];
                af = *reinterpret_cast<const bf16x8*>(&lds[Ab + aoff[kk]]);
#pragma unroll
                for (int ni = 0; ni < 2; ni++)
                    bfr[ni] = *reinterpret_cast<const bf16x8*>(&lds[Bb + boff[ni][kk]]);
#pragma unroll
                for (int ni = 0; ni < 2; ni++)
                    acc[ni] = __builtin_amdgcn_mfma_f32_16x16x32_bf16(
                        af, bfr[ni], acc[ni], 0, 0, 0);
            }
        }
    }

    {
        int mbase = m0 + wm * 16 + (lane >> 4) * 4;
#pragma unroll
        for (int ni = 0; ni < 2; ni++) {
            int n = n0 + wn * 32 + ni * 16 + (lane & 15);
            if (epi == 0) {
#pragma unroll
                for (int r = 0; r < 4; r++) {
                    float v = acc[ni][r];
                    Cp[(size_t)(mbase + r) * N + n] = v;
                    if (Hout) {
                        unsigned short hb = f2bf(v);
                        unsigned short lb = f2bf(v - bf2f(hb));
                        size_t ho = (size_t)(hrow0 + mbase + r) * N + n;
                        Hout[ho] = hb;
                        Lout[ho] = lb;
                    }
                }
            } else {
                float bo = bias ? ldg1(bias, n, flag) : 0.f;
#pragma unroll
                for (int r = 0; r < 4; r++) {
                    float v = acc[ni][r] + bo;
                    size_t off = (size_t)(mbase + r) * N + n;
                    if (flag) ((unsigned short*)O)[off] = f2bf(v);
                    else      ((float*)O)[off] = v;
                }
            }
        }
    }
}

// ---------------------------------------------------------------------------
// Merged scqh + kv launch (1280 blocks): bid<768 -> scores/qh GEMM on
// pre-split bf16 (BM=128/BN=64, gload_lds staging, 3-pass); bid>=768 ->
// Kp/Vp projection (BM=32/BN=64, reg-staged, rowscale, 3-pass). kv blocks
// backfill the scqh tail. NOTE: Vp must NOT alias KWf (topk fallback reads
// KWf after this launch) — Vp has a dedicated region.
// ---------------------------------------------------------------------------
__global__ __launch_bounds__(256) void gemm_scqh_kv(
    const unsigned short* __restrict__ Xh, const unsigned short* __restrict__ Xl,
    const unsigned short* __restrict__ Bh, const unsigned short* __restrict__ Bl,
    float* __restrict__ Sc, float* __restrict__ qh,
    const void* __restrict__ keys, const void* __restrict__ Wk,
    const float* __restrict__ inv_kf, float* __restrict__ Kp,
    const void* __restrict__ vals, const void* __restrict__ Wv,
    const float* __restrict__ inv_vf, float* __restrict__ Vp,
    const void* __restrict__ gdet)
{
    __shared__ __align__(16) short lds[24576];
    const int t = threadIdx.x;
    const int bid = blockIdx.x;
    const int lane = t & 63, wv = t >> 6;
    const int wm = wv >> 1, wn = wv & 1;

    if (bid < 768) {
        // ================= scqh body =================
        const int AHo = 0, ALo = 8192, BHo = 16384, BLo = 20480;
        const int m0 = (bid / 24) * 128, n0 = (bid % 24) * 64;
        const int lr = lane >> 3, lc = lane & 7;

        int aoff[4][2], boff[2][2];
#pragma unroll
        for (int mi = 0; mi < 4; mi++)
#pragma unroll
            for (int kk = 0; kk < 2; kk++) {
                int ra = wm * 64 + mi * 16 + (lane & 15);
                int ca = kk * 4 + (lane >> 4);
                aoff[mi][kk] = ra * 64 + ((ca ^ (ra & 7)) << 3);
            }
#pragma unroll
        for (int ni = 0; ni < 2; ni++)
#pragma unroll
            for (int kk = 0; kk < 2; kk++) {
                int rb = wn * 32 + ni * 16 + (lane & 15);
                int cb = kk * 4 + (lane >> 4);
                boff[ni][kk] = rb * 64 + ((cb ^ (rb & 7)) << 3);
            }

        f32x4 acc[4][2];
#pragma unroll
        for (int mi = 0; mi < 4; mi++)
#pragma unroll
            for (int ni = 0; ni < 2; ni++)
                acc[mi][ni] = (f32x4){0.f, 0.f, 0.f, 0.f};

        char* smem = (char*)lds;

        for (int ks = 0; ks < 5; ks++) {
            const int kb = ks * 64;
            __syncthreads();
#pragma unroll
            for (int i = 0; i < 4; i++) {
                int r0 = wv * 32 + i * 8;
                int r  = r0 + lr;
                int sc = lc ^ (r & 7);
                size_t go = (size_t)(m0 + r) * 320 + kb + sc * 8;
                gload16(Xh + go, smem + (AHo << 1) + r0 * 128);
                gload16(Xl + go, smem + (ALo << 1) + r0 * 128);
            }
#pragma unroll
            for (int i = 0; i < 2; i++) {
                int r0 = wv * 16 + i * 8;
                int r  = r0 + lr;
                int sc = lc ^ (r & 7);
                size_t go = (size_t)(n0 + r) * 320 + kb + sc * 8;
                gload16(Bh + go, smem + (BHo << 1) + r0 * 128);
                gload16(Bl + go, smem + (BLo << 1) + r0 * 128);
            }
            __syncthreads();
#pragma unroll
            for (int p = 0; p < 3; p++) {
                const int Ab = (p == 1) ? ALo : AHo;
                const int Bb = (p == 2) ? BLo : BHo;
#pragma unroll
                for (int kk = 0; kk < 2; kk++) {
                    bf16x8 af[4], bfr[2];
#pragma unroll
                    for (int mi = 0; mi < 4; mi++)
                        af[mi] = *reinterpret_cast<const bf16x8*>(&lds[Ab + aoff[mi][kk]]);
#pragma unroll
                    for (int ni = 0; ni < 2; ni++)
                        bfr[ni] = *reinterpret_cast<const bf16x8*>(&lds[Bb + boff[ni][kk]]);
#pragma unroll
                    for (int mi = 0; mi < 4; mi++)
#pragma unroll
                        for (int ni = 0; ni < 2; ni++)
                            acc[mi][ni] = __builtin_amdgcn_mfma_f32_16x16x32_bf16(
                                af[mi], bfr[ni], acc[mi][ni], 0, 0, 0);
                }
            }
        }

#pragma unroll
        for (int mi = 0; mi < 4; mi++) {
            int mbase = m0 + wm * 64 + mi * 16 + (lane >> 4) * 4;
#pragma unroll
            for (int ni = 0; ni < 2; ni++) {
                int n = n0 + wn * 32 + ni * 16 + (lane & 15);
#pragma unroll
                for (int r = 0; r < 4; r++) {
                    float v = acc[mi][ni][r];
                    int m = mbase + r;
                    if (n0 < 1024) Sc[(size_t)m * 1024 + n] = v;
                    else           qh[(size_t)m * 512 + (n - 1024)] = v;
                }
            }
        }
    } else {
        // ================= kv body (BM=32, BN=64, 3-pass, rowscale) =======
        const int AHk = 0, ALk = 2048, BHk = 4096, BLk = 8192;
        int kb_ = bid - 768;               // 0..511
        int x = kb_ & 7, y = kb_ >> 3;     // x:0..7, y:0..63
        const int flag = detect_bf(gdet);
        const void* Ap; const void* Bp; const float* scp; float* Cp;
        if (y < 32) { Ap = keys; Bp = Wk; scp = inv_kf; Cp = Kp; }
        else        { Ap = vals; Bp = Wv; scp = inv_vf; Cp = Vp; y -= 32; }
        const int m0 = y * 32, n0 = x * 64;
        const int srow = t >> 3, sc8 = t & 7;

        int aoff[2], boff[2][2];
#pragma unroll
        for (int kk = 0; kk < 2; kk++) {
            int ra = wm * 16 + (lane & 15);
            int ca = kk * 4 + (lane >> 4);
            aoff[kk] = ra * 64 + ((ca ^ (ra & 7)) << 3);
        }
#pragma unroll
        for (int ni = 0; ni < 2; ni++)
#pragma unroll
            for (int kk = 0; kk < 2; kk++) {
                int rb = wn * 32 + ni * 16 + (lane & 15);
                int cb = kk * 4 + (lane >> 4);
                boff[ni][kk] = rb * 64 + ((cb ^ (rb & 7)) << 3);
            }

        const int addr0 = srow * 64 + ((sc8 ^ (srow & 7)) << 3);
        const int addr1 = addr0 + 32 * 64;
        const float s0 = scp[m0 + srow];

        f32x4 acc[2];
        acc[0] = (f32x4){0.f, 0.f, 0.f, 0.f};
        acc[1] = (f32x4){0.f, 0.f, 0.f, 0.f};

        float av0[8], bv0[8], bv1[8];
        ld4(Ap, (size_t)(m0 + srow) * 512 + sc8 * 8,          flag, av0);
        ld4(Ap, (size_t)(m0 + srow) * 512 + sc8 * 8 + 4,      flag, av0 + 4);
        ld4(Bp, (size_t)(n0 + srow) * 512 + sc8 * 8,          flag, bv0);
        ld4(Bp, (size_t)(n0 + srow) * 512 + sc8 * 8 + 4,      flag, bv0 + 4);
        ld4(Bp, (size_t)(n0 + srow + 32) * 512 + sc8 * 8,     flag, bv1);
        ld4(Bp, (size_t)(n0 + srow + 32) * 512 + sc8 * 8 + 4, flag, bv1 + 4);

        for (int ks = 0; ks < 8; ks++) {
            const int kb = ks * 64;
            float a0[8], b0[8], b1[8];
#pragma unroll
            for (int j = 0; j < 8; j++) { a0[j] = av0[j] * s0; b0[j] = bv0[j]; b1[j] = bv1[j]; }
            u32x4 ah0, al0, bh0, bl0, bh1, bl1;
            split8(a0, ah0, al0);
            split8(b0, bh0, bl0); split8(b1, bh1, bl1);
            __syncthreads();
            *reinterpret_cast<u32x4*>(&lds[AHk + addr0]) = ah0;
            *reinterpret_cast<u32x4*>(&lds[ALk + addr0]) = al0;
            *reinterpret_cast<u32x4*>(&lds[BHk + addr0]) = bh0;
            *reinterpret_cast<u32x4*>(&lds[BHk + addr1]) = bh1;
            *reinterpret_cast<u32x4*>(&lds[BLk + addr0]) = bl0;
            *reinterpret_cast<u32x4*>(&lds[BLk + addr1]) = bl1;
            __syncthreads();
            if (ks < 7) {
                const int kn = kb + 64;
                ld4(Ap, (size_t)(m0 + srow) * 512 + kn + sc8 * 8,          flag, av0);
                ld4(Ap, (size_t)(m0 + srow) * 512 + kn + sc8 * 8 + 4,      flag, av0 + 4);
                ld4(Bp, (size_t)(n0 + srow) * 512 + kn + sc8 * 8,          flag, bv0);
                ld4(Bp, (size_t)(n0 + srow) * 512 + kn + sc8 * 8 + 4,      flag, bv0 + 4);
                ld4(Bp, (size_t)(n0 + srow + 32) * 512 + kn + sc8 * 8,     flag, bv1);
                ld4(Bp, (size_t)(n0 + srow + 32) * 512 + kn + sc8 * 8 + 4, flag, bv1 + 4);
            }
#pragma unroll
            for (int p = 0; p < 3; p++) {
                const int Ab = (p == 1) ? ALk : AHk;
                const int Bb = (p == 2) ? BLk : BHk;
#pragma unroll
                for (int kk = 0; kk < 2; kk++) {
                    bf16x8 af, bfr[2];
                    af = *reinterpret_cast<const bf16x8*>(&lds[Ab + aoff[kk]]);
#pragma unroll
                    for (int ni = 0; ni < 2; ni++)
                        bfr[ni] = *reinterpret_cast<const bf16x8*>(&lds[Bb + boff[ni][kk]]);
#pragma unroll
                    for (int ni = 0; ni < 2; ni++)
                        acc[ni] = __builtin_amdgcn_mfma_f32_16x16x32_bf16(
                            af, bfr[ni], acc[ni], 0, 0, 0);
                }
            }
        }

        int mbase = m0 + wm * 16 + (lane >> 4) * 4;
#pragma unroll
        for (int ni = 0; ni < 2; ni++) {
            int n = n0 + wn * 32 + ni * 16 + (lane & 15);
#pragma unroll
            for (int r = 0; r < 4; r++)
                Cp[(size_t)(mbase + r) * 512 + n] = acc[ni][r];
        }
    }
}

// ---------------------------------------------------------------------------
// Top-32 select, one wave per row. Binary search seeded with [rowmin,
// rowmax+1] (same invariant, same selection, ~40% fewer iterations).
// Fallback re-score: fp32 KWf (4-pass-MFMA accurate) with fp64 dot.
// ---------------------------------------------------------------------------
__global__ __launch_bounds__(256) void topk_select(
    const float* __restrict__ Sc, const void* __restrict__ X,
    const void* __restrict__ gdet, const float* __restrict__ KWf,
    int* __restrict__ idx)
{
    __shared__ unsigned int srow[4][1024];
    __shared__ unsigned int scv[4][64];
    __shared__ int          sci[4][64];
    const int bf = detect_bf(gdet);
    const int w = threadIdx.x >> 6, lane = threadIdx.x & 63;
    const int row = blockIdx.x * 4 + w;
    const float* S = Sc + (size_t)row * 1024;

    unsigned int mn = 0xFFFFFFFFu, mx = 0u;
#pragma unroll
    for (int q = 0; q < 4; q++) {
        float4 v = *reinterpret_cast<const float4*>(&S[lane * 4 + q * 256]);
        uint4 k = make_uint4(fkey(v.x), fkey(v.y), fkey(v.z), fkey(v.w));
        *reinterpret_cast<uint4*>(&srow[w][lane * 4 + q * 256]) = k;
        mn = min(mn, min(min(k.x, k.y), min(k.z, k.w)));
        mx = max(mx, max(max(k.x, k.y), max(k.z, k.w)));
    }
    scv[w][lane] = 0u;
    sci[w][lane] = 0x7FFFFFFF;
#pragma unroll
    for (int o = 1; o < 64; o <<= 1) {
        mn = min(mn, __shfl_xor(mn, o, 64));
        mx = max(mx, __shfl_xor(mx, o, 64));
    }
    __syncthreads();

    unsigned int lo = mn;
    unsigned int hi = (mx == 0xFFFFFFFFu) ? 0xFFFFFFFFu : mx + 1u;
    int cnt_lo = 1024;
    while (cnt_lo > 48 && hi - lo > 1u) {
        unsigned int mid = lo + ((hi - lo) >> 1);
        int c = 0;
#pragma unroll
        for (int q = 0; q < 4; q++) {
            uint4 k = *reinterpret_cast<const uint4*>(&srow[w][lane * 4 + q * 256]);
            c += (k.x >= mid) + (k.y >= mid) + (k.z >= mid) + (k.w >= mid);
        }
#pragma unroll
        for (int o = 1; o < 64; o <<= 1) c += __shfl_xor(c, o, 64);
        if (c >= 33) { lo = mid; cnt_lo = c; }
        else hi = mid;
    }
    const unsigned int T = lo;

    int cl = 0;
#pragma unroll
    for (int q = 0; q < 4; q++) {
        uint4 k = *reinterpret_cast<const uint4*>(&srow[w][lane * 4 + q * 256]);
        cl += (k.x >= T) + (k.y >= T) + (k.z >= T) + (k.w >= T);
    }
    int inc = cl;
#pragma unroll
    for (int o = 1; o < 64; o <<= 1) {
        int y = __shfl_up(inc, o, 64);
        if (lane >= o) inc += y;
    }
    int pos = inc - cl;
#pragma unroll
    for (int q = 0; q < 4; q++) {
        uint4 k = *reinterpret_cast<const uint4*>(&srow[w][lane * 4 + q * 256]);
        int base = lane * 4 + q * 256;
        if (k.x >= T && pos < 64) { scv[w][pos] = k.x; sci[w][pos] = base + 0; pos++; }
        if (k.y >= T && pos < 64) { scv[w][pos] = k.y; sci[w][pos] = base + 1; pos++; }
        if (k.z >= T && pos < 64) { scv[w][pos] = k.z; sci[w][pos] = base + 2; pos++; }
        if (k.w >= T && pos < 64) { scv[w][pos] = k.w; sci[w][pos] = base + 3; pos++; }
    }
    __syncthreads();
    unsigned int cv = scv[w][lane];
    int          ci = sci[w][lane];
#pragma unroll
    for (int k = 2; k <= 64; k <<= 1) {
#pragma unroll
        for (int jj = k >> 1; jj > 0; jj >>= 1) {
            unsigned int ov = __shfl_xor(cv, jj, 64);
            int          oi = __shfl_xor(ci, jj, 64);
            bool up = ((lane & k) == 0);
            bool takemax = (((lane & jj) == 0) == up);
            bool othergreater = (ov > cv) || (ov == cv && oi < ci);
            if (takemax == othergreater) { cv = ov; ci = oi; }
        }
    }
    float v31 = funkey(__shfl(cv, 31, 64));
    float v32 = funkey(__shfl(cv, 32, 64));
    if (v31 - v32 > 2.5e-4f) {
        if (lane < 32) idx[(size_t)row * 32 + lane] = ci;
        return;
    }
    size_t xb = (size_t)row * 320;
    bool active = (lane < 48) && (ci != 0x7FFFFFFF);
    int cidx = active ? ci : 0x7FFFFFFF;
    const float* kr = KWf + (size_t)(active ? ci : 0) * 320;
    double s = 0.0;
#pragma unroll 4
    for (int d = 0; d < 320; d++) {
        float xd = ldg1(X, xb + d, bf);
        s += (double)xd * (double)kr[d];
    }
    if (!active) s = -1.0e300;
#pragma unroll
    for (int k = 2; k <= 64; k <<= 1) {
#pragma unroll
        for (int jj = k >> 1; jj > 0; jj >>= 1) {
            double os = __shfl_xor(s, jj, 64);
            int    oi = __shfl_xor(cidx, jj, 64);
            bool up = ((lane & k) == 0);
            bool takemax = (((lane & jj) == 0) == up);
            bool og = (os > s) || (os == s && oi < cidx);
            if (takemax == og) { s = os; cidx = oi; }
        }
    }
    if (lane < 32) idx[(size_t)row * 32 + lane] = cidx;
}

// ---------------------------------------------------------------------------
// Fused gather + 8-head attention per row. QK: one wave per slot-row,
// coalesced full-line reads + 8-lane-group shuffle reduce. PV: float2 cols.
// ---------------------------------------------------------------------------
__global__ __launch_bounds__(256) void attn_kernel(
    const float* __restrict__ qh, const float* __restrict__ Kp,
    const float* __restrict__ Vp, const int* __restrict__ idx,
    float* __restrict__ ctx)
{
    __shared__ float sq[512];
    __shared__ int   sidx[32];
    __shared__ float sl[8][32];
    __shared__ float sw[8][32];
    int row = blockIdx.x, t = threadIdx.x;
    int w = t >> 6, l = t & 63;
    if (t < 128)
        *reinterpret_cast<float4*>(&sq[t * 4]) =
            *reinterpret_cast<const float4*>(&qh[(size_t)row * 512 + t * 4]);
    if (t < 32) {
        int v = idx[(size_t)row * 32 + t];
        sidx[t] = (v < 0) ? 0 : (v > 1023 ? 1023 : v);
    }
    __syncthreads();

    float4 q0 = *reinterpret_cast<const float4*>(&sq[l * 8]);
    float4 q1 = *reinterpret_cast<const float4*>(&sq[l * 8 + 4]);
    int h = l >> 3;
#pragma unroll
    for (int i = 0; i < 8; i++) {
        int s = w * 8 + i;
        const float* kp = Kp + (size_t)sidx[s] * 512 + l * 8;
        float4 k0 = *reinterpret_cast<const float4*>(kp);
        float4 k1 = *reinterpret_cast<const float4*>(kp + 4);
        float p = q0.x * k0.x + q0.y * k0.y + q0.z * k0.z + q0.w * k0.w
                + q1.x * k1.x + q1.y * k1.y + q1.z * k1.z + q1.w * k1.w;
        p += __shfl_xor(p, 1, 64);
        p += __shfl_xor(p, 2, 64);
        p += __shfl_xor(p, 4, 64);
        if ((l & 7) == 0) sl[h][s] = p * 0.125f;
    }
    __syncthreads();

    int hh = t >> 5, kk = t & 31;
    float logit = sl[hh][kk];
    float m = -1e30f;
#pragma unroll
    for (int i = 0; i < 32; i++) m = fmaxf(m, sl[hh][i]);
    float ssum = 0.f;
#pragma unroll
    for (int i = 0; i < 32; i++) ssum += __expf(sl[hh][i] - m);
    sw[hh][kk] = __expf(logit - m) / ssum;
    __syncthreads();

    int c = t * 2, hc = c >> 6;
    float ax = 0.f, ay = 0.f;
#pragma unroll
    for (int k2 = 0; k2 < 32; k2++) {
        float2 vv = *reinterpret_cast<const float2*>(&Vp[(size_t)sidx[k2] * 512 + c]);
        float wgt = sw[hc][k2];
        ax += wgt * vv.x; ay += wgt * vv.y;
    }
    *reinterpret_cast<float2*>(&ctx[(size_t)row * 512 + c]) = make_float2(ax, ay);
}

extern "C" void kernel_launch(void* const* d_in, const int* in_sizes, int n_in,
                              void* d_out, int out_size, void* d_ws, size_t ws_size,
                              hipStream_t stream)
{
    const void* X    = d_in[0];
    const void* Wqp  = d_in[1];
    const void* keys = d_in[2];
    const void* vals = d_in[3];
    const void* Wq   = d_in[4];
    const void* Wk   = d_in[5];
    const void* Wv   = d_in[6];
    const void* Wo   = d_in[7];
    const void* ln_g = d_in[8];
    const void* ln_b = d_in[9];
    const void* Wout = d_in[10];
    const void* bout = d_in[11];

    // ---- workspace (float units; ~43 MiB of the 256 MiB pool) ----
    float* ws = (float*)d_ws;
    float*  Sc     = ws;                       // 4096x1024 fp32
    float*  co     = ws;                       // reuses Sc region after topk
    float*  Yreg   = ws + 2097152;             // ctx (post-topk)
    float*  qh     = ws + 4194304;             // 4096x512
    float*  Mf     = ws + 6291456;             // 512*320 (Kp region; Mf dead after prep)
    float*  Kp     = ws + 6291456;
    float*  KWf    = ws + 6815744;             // 1024*320 — read by topk; no alias!
    float*  WqpT   = ws + 7340032;             // 320*512 fp32
    int*    idx    = (int*)(ws + 7995392);
    float*  inv_kf = ws + 8128512;
    float*  inv_vf = ws + 8129536;
    unsigned short* Xh  = (unsigned short*)(ws + 8388608);   // 4096x320 bf16
    unsigned short* Xl  = (unsigned short*)(ws + 9043968);
    unsigned short* Bh  = (unsigned short*)(ws + 9699328);   // 1536x320 bf16
    unsigned short* Bl  = (unsigned short*)(ws + 9945088);
    float*  Vp     = ws + 10190848;            // 1024x512 — DEDICATED (was
                                               // aliasing KWf: race w/ merged
                                               // scqh_kv before topk, round 8 fix)
    float*  ctx    = Yreg;

    // fused norms + WqpT transpose + X presplit (2048 + 160 + 640 blocks)
    prep_fused<<<2848, 256, 0, stream>>>(
        keys, vals, Wqp, X, ln_g, inv_kf, inv_vf, WqpT, Xh, Xl);
    // merged KWf (rowscale(keys)@WqpT^T, 4-pass: fp32-accurate for tie-break)
    // + Mf (Wq@WqpT^T); also emits bf16 h/l into stacked Bh/Bl [1536][320].
    mfma_abt<<<dim3(5, 48), 256, 0, stream>>>(
        keys, WqpT, inv_kf, KWf, Wq, WqpT, nullptr, Mf, 32,
        nullptr, nullptr, nullptr, nullptr, nullptr,
        Bh, Bl, 0, 1024,
        320, 1, 1, 0, 0, 4, ln_g);
    // merged scores/qh GEMM (768 blocks) + Kp/Vp projection (512 blocks)
    gemm_scqh_kv<<<1280, 256, 0, stream>>>(
        Xh, Xl, Bh, Bl, Sc, qh,
        keys, Wk, inv_kf, Kp, vals, Wv, inv_vf, Vp, ln_g);
    topk_select<<<1024, 256, 0, stream>>>(Sc, X, ln_g, KWf, idx);
    attn_kernel<<<4096, 256, 0, stream>>>(qh, Kp, Vp, idx, ctx);
    // ctx @ Wo^T -> co (split-MFMA, 3-pass), 1024 blocks = 4/CU
    mfma_abt<<<dim3(8, 128), 256, 0, stream>>>(
        ctx, Wo, nullptr, co, nullptr, nullptr, nullptr, nullptr, 0,
        nullptr, nullptr, nullptr, nullptr, nullptr,
        nullptr, nullptr, 0, 0,
        512, 0, 0, 1, 0, 3, ln_g);
    // out = (LN(co)*g+b) @ Wout^T + bout; LN stats computed in-kernel
    // (stats=nullptr -> fp64 pre-pass over co), 640 blocks
    mfma_abt<<<dim3(5, 128), 256, 0, stream>>>(
        co, Wout, nullptr, nullptr, nullptr, nullptr, nullptr, nullptr, 0,
        nullptr, ln_g, ln_b, bout, d_out,
        nullptr, nullptr, 0, 0,
        320, 2, 0, 1, 1, 3, ln_g);
}

// Round 10
// 227.222 us; speedup vs baseline: 1.0226x; 1.0226x over previous
//
#include <hip/hip_runtime.h>

// GatedLTMMemory: 4096 rows, QD=320, D=512, S=1024, H=8, K=32, DH=64
// Dtype (fp32 vs bf16) derived inline from ln_g[0] (== 1.0). (Resolved: fp32.)

__device__ __forceinline__ float bf2f(unsigned short u) {
    return __uint_as_float(((unsigned int)u) << 16);
}
__device__ __forceinline__ unsigned short f2bf(float f) {
    unsigned int u = __float_as_uint(f);
    u += 0x7FFFu + ((u >> 16) & 1u);
    return (unsigned short)(u >> 16);
}
__device__ __forceinline__ int detect_bf(const void* g) {
    return ((*(const unsigned int*)g) & 0xFFFFu) != 0u;
}
__device__ __forceinline__ float ldg1(const void* p, size_t i, int bf) {
    return bf ? bf2f(((const unsigned short*)p)[i]) : ((const float*)p)[i];
}
__device__ __forceinline__ void ld4(const void* p, size_t i, int bf, float* o) {
    if (bf) {
        ushort4 v = *reinterpret_cast<const ushort4*>((const unsigned short*)p + i);
        o[0] = bf2f(v.x); o[1] = bf2f(v.y); o[2] = bf2f(v.z); o[3] = bf2f(v.w);
    } else {
        float4 v = *reinterpret_cast<const float4*>((const float*)p + i);
        o[0] = v.x; o[1] = v.y; o[2] = v.z; o[3] = v.w;
    }
}
__device__ __forceinline__ unsigned int fkey(float x) {
    unsigned int u = __float_as_uint(x);
    return (u & 0x80000000u) ? ~u : (u | 0x80000000u);
}
__device__ __forceinline__ float funkey(unsigned int k) {
    unsigned int u = (k & 0x80000000u) ? (k & 0x7FFFFFFFu) : ~k;
    return __uint_as_float(u);
}

typedef __attribute__((ext_vector_type(8))) short bf16x8;
typedef __attribute__((ext_vector_type(4))) float f32x4;
typedef __attribute__((ext_vector_type(4))) unsigned int u32x4;

// split 8 fp32 into hi/lo bf16 packs via v_cvt_pk_bf16_f32 (RNE):
// x ~= bf2f(hi) + bf2f(lo); residual ~2^-17|x| (captured by 4-pass).
__device__ __forceinline__ void split8(const float* x, u32x4& h, u32x4& l) {
#pragma unroll
    for (int j = 0; j < 4; j++) {
        float x0 = x[2 * j], x1 = x[2 * j + 1];
        unsigned int hp, lp;
        asm("v_cvt_pk_bf16_f32 %0, %1, %2" : "=v"(hp) : "v"(x0), "v"(x1));
        float h0 = __uint_as_float(hp << 16);
        float h1 = __uint_as_float(hp & 0xFFFF0000u);
        float l0 = x0 - h0, l1 = x1 - h1;
        asm("v_cvt_pk_bf16_f32 %0, %1, %2" : "=v"(lp) : "v"(l0), "v"(l1));
        h[j] = hp; l[j] = lp;
    }
}

// async global -> LDS, 16 bytes per lane. LDS dest = wave-uniform base +
// lane*16 (linear); per-lane global source (pre-swizzled by caller).
__device__ __forceinline__ void gload16(const void* g, void* l) {
    __builtin_amdgcn_global_load_lds(
        (const __attribute__((address_space(1))) unsigned int*)g,
        (__attribute__((address_space(3))) unsigned int*)l,
        16, 0, 0);
}

// ---------------------------------------------------------------------------
// Fused prep: blockIdx.x < 2048 -> norms; < 2208 -> WqpT transpose;
// else presplit X (640 blocks).
// ---------------------------------------------------------------------------
__global__ __launch_bounds__(256) void prep_fused(
    const void* __restrict__ keys, const void* __restrict__ vals,
    const void* __restrict__ Wqp, const void* __restrict__ X,
    const void* __restrict__ gdet,
    float* __restrict__ inv_kf, float* __restrict__ inv_vf,
    float* __restrict__ WqpT,
    unsigned short* __restrict__ Xh, unsigned short* __restrict__ Xl)
{
    __shared__ double red[256];
    __shared__ float tile[32][36];
    const int bf = detect_bf(gdet);
    const int bid = blockIdx.x, t = threadIdx.x;
    if (bid < 2048) {
        int r = bid;
        const void* src = (r < 1024) ? keys : vals;
        size_t base = (size_t)((r < 1024) ? r : r - 1024) * 512;
        float x0 = ldg1(src, base + t, bf), x1 = ldg1(src, base + t + 256, bf);
        red[t] = (double)x0 * x0 + (double)x1 * x1;
        __syncthreads();
        for (int s = 128; s > 0; s >>= 1) {
            if (t < s) red[t] += red[t + s];
            __syncthreads();
        }
        if (t == 0) {
            float rs = (float)(1.0 / sqrt(red[0] + 1e-12));
            if (r < 1024) inv_kf[r] = rs;
            else          inv_vf[r - 1024] = rs;
        }
    } else if (bid < 2208) {
        int tid = bid - 2048;                 // 160 blocks: 16 x 10
        int d0 = (tid & 15) * 32, q0 = (tid >> 4) * 32;
        int r = t >> 3, c = (t & 7) * 4;
        float v[4];
        ld4(Wqp, (size_t)(d0 + r) * 320 + q0 + c, bf, v);
#pragma unroll
        for (int i = 0; i < 4; i++) tile[r][c + i] = v[i];
        __syncthreads();
        float o[4];
#pragma unroll
        for (int i = 0; i < 4; i++) o[i] = tile[c + i][r];
        *reinterpret_cast<float4*>(&WqpT[(size_t)(q0 + r) * 512 + d0 + c]) =
            make_float4(o[0], o[1], o[2], o[3]);
    } else {
        int i = (bid - 2208) * 256 + t;       // 640 blocks x 256 = 163840
        float v[8];
        ld4(X, (size_t)i * 8, bf, v);
        ld4(X, (size_t)i * 8 + 4, bf, v + 4);
        u32x4 h, l;
        split8(v, h, l);
        *reinterpret_cast<u32x4*>(Xh + (size_t)i * 8) = h;
        *reinterpret_cast<u32x4*>(Xl + (size_t)i * 8) = l;
    }
}

// ---------------------------------------------------------------------------
// Unified split-MFMA ABT: C = rowop(A) @ B^T, K=512 fixed, bf16 split
// emulation. npass=3: Ah·Bh+Al·Bh+Ah·Bl (err ~3e-5). npass=4: +Al·Bl
// (fp32-GEMM-accurate). BM=32, BN=64, BK=64, 4 waves, wave=16x32.
// LDS 24 KB, XOR chunk swizzle. T14 prefetch after the 2nd barrier.
// amode 2 with stats==nullptr: compute LN stats in-kernel (pre-pass over A,
// fp64 accumulate + 8-lane shuffle reduce — ln_stats-equivalent).
// ---------------------------------------------------------------------------
__global__ __launch_bounds__(256) void mfma_abt(
    const void* __restrict__ A, const void* __restrict__ B,
    const float* __restrict__ scale, float* __restrict__ C,
    const void* __restrict__ A2, const void* __restrict__ B2,
    const float* __restrict__ scale2, float* __restrict__ C2, int ysplit,
    const float2* __restrict__ stats, const void* __restrict__ g,
    const void* __restrict__ bvec, const void* __restrict__ bias,
    void* __restrict__ O,
    unsigned short* __restrict__ Hout, unsigned short* __restrict__ Lout,
    int hrow0a, int hrow0b,
    int N, int amode, int abfon, int bbfon, int epi, int npass,
    const void* __restrict__ gdet)
{
    __shared__ __align__(16) short lds[12288];
    const int AHo = 0, ALo = 2048, BHo = 4096, BLo = 8192;  // short units
    const int flag = detect_bf(gdet);
    const int abf = abfon ? flag : 0;
    const int bbf = bbfon ? flag : 0;
    const int t = threadIdx.x;
    int by = blockIdx.y;
    const void* Ap = A; const void* Bp = B;
    const float* scp = scale; float* Cp = C;
    int hrow0 = hrow0a;
    if (ysplit && by >= ysplit) {
        Ap = A2; Bp = B2; scp = scale2; Cp = C2; by -= ysplit; hrow0 = hrow0b;
    }
    const int m0 = by * 32, n0 = blockIdx.x * 64;
    const int lane = t & 63, wv = t >> 6;
    const int wm = wv >> 1, wn = wv & 1;
    const int srow = t >> 3;   // 0..31
    const int sc8  = t & 7;    // chunk of 8 elements

    int aoff[2], boff[2][2];
#pragma unroll
    for (int kk = 0; kk < 2; kk++) {
        int ra = wm * 16 + (lane & 15);
        int ca = kk * 4 + (lane >> 4);
        aoff[kk] = ra * 64 + ((ca ^ (ra & 7)) << 3);
    }
#pragma unroll
    for (int ni = 0; ni < 2; ni++)
#pragma unroll
        for (int kk = 0; kk < 2; kk++) {
            int rb = wn * 32 + ni * 16 + (lane & 15);
            int cb = kk * 4 + (lane >> 4);
            boff[ni][kk] = rb * 64 + ((cb ^ (rb & 7)) << 3);
        }

    const int addr0 = srow * 64 + ((sc8 ^ (srow & 7)) << 3);
    const int addr1 = addr0 + 32 * 64;   // (srow+32)&7 == srow&7

    float s0 = 1.0f;
    float2 st0 = make_float2(0.f, 1.f);
    if (amode == 1) {
        s0 = scp ? scp[m0 + srow] : 1.0f;
    } else if (amode == 2) {
        if (stats) {
            st0 = stats[m0 + srow];
        } else {
            // inline LN stats: row srow covered by the 8 threads sc8=0..7
            double s = 0.0, ss = 0.0;
            for (int kb2 = 0; kb2 < 512; kb2 += 64) {
                float v8[8];
                ld4(Ap, (size_t)(m0 + srow) * 512 + kb2 + sc8 * 8,     abf, v8);
                ld4(Ap, (size_t)(m0 + srow) * 512 + kb2 + sc8 * 8 + 4, abf, v8 + 4);
#pragma unroll
                for (int j = 0; j < 8; j++) {
                    s  += (double)v8[j];
                    ss += (double)v8[j] * v8[j];
                }
            }
            s  += __shfl_xor(s, 1, 64);  ss += __shfl_xor(ss, 1, 64);
            s  += __shfl_xor(s, 2, 64);  ss += __shfl_xor(ss, 2, 64);
            s  += __shfl_xor(s, 4, 64);  ss += __shfl_xor(ss, 4, 64);
            double mu = s / 512.0, var = ss / 512.0 - mu * mu;
            st0 = make_float2((float)mu, (float)(1.0 / sqrt(var + 1e-5)));
        }
    }

    f32x4 acc[2];
    acc[0] = (f32x4){0.f, 0.f, 0.f, 0.f};
    acc[1] = (f32x4){0.f, 0.f, 0.f, 0.f};

    float av0[8], bv0[8], bv1[8];
    {
        ld4(Ap, (size_t)(m0 + srow) * 512 + sc8 * 8,          abf, av0);
        ld4(Ap, (size_t)(m0 + srow) * 512 + sc8 * 8 + 4,      abf, av0 + 4);
        ld4(Bp, (size_t)(n0 + srow) * 512 + sc8 * 8,          bbf, bv0);
        ld4(Bp, (size_t)(n0 + srow) * 512 + sc8 * 8 + 4,      bbf, bv0 + 4);
        ld4(Bp, (size_t)(n0 + srow + 32) * 512 + sc8 * 8,     bbf, bv1);
        ld4(Bp, (size_t)(n0 + srow + 32) * 512 + sc8 * 8 + 4, bbf, bv1 + 4);
    }

    for (int ks = 0; ks < 8; ks++) {
        const int kb = ks * 64;
        float a0[8], b0[8], b1[8];
#pragma unroll
        for (int j = 0; j < 8; j++) { a0[j] = av0[j]; b0[j] = bv0[j]; b1[j] = bv1[j]; }
        if (amode == 1) {
#pragma unroll
            for (int j = 0; j < 8; j++) a0[j] *= s0;
        } else if (amode == 2) {
            float gv[8], bv8[8];
            ld4(g,    (size_t)(kb + sc8 * 8),     flag, gv);
            ld4(g,    (size_t)(kb + sc8 * 8 + 4), flag, gv + 4);
            ld4(bvec, (size_t)(kb + sc8 * 8),     flag, bv8);
            ld4(bvec, (size_t)(kb + sc8 * 8 + 4), flag, bv8 + 4);
#pragma unroll
            for (int j = 0; j < 8; j++)
                a0[j] = (a0[j] - st0.x) * st0.y * gv[j] + bv8[j];
        }
        u32x4 ah0, al0, bh0, bl0, bh1, bl1;
        split8(a0, ah0, al0);
        split8(b0, bh0, bl0); split8(b1, bh1, bl1);
        __syncthreads();
        *reinterpret_cast<u32x4*>(&lds[AHo + addr0]) = ah0;
        *reinterpret_cast<u32x4*>(&lds[ALo + addr0]) = al0;
        *reinterpret_cast<u32x4*>(&lds[BHo + addr0]) = bh0;
        *reinterpret_cast<u32x4*>(&lds[BHo + addr1]) = bh1;
        *reinterpret_cast<u32x4*>(&lds[BLo + addr0]) = bl0;
        *reinterpret_cast<u32x4*>(&lds[BLo + addr1]) = bl1;
        __syncthreads();
        if (ks < 7) {
            const int kn = kb + 64;
            ld4(Ap, (size_t)(m0 + srow) * 512 + kn + sc8 * 8,          abf, av0);
            ld4(Ap, (size_t)(m0 + srow) * 512 + kn + sc8 * 8 + 4,      abf, av0 + 4);
            ld4(Bp, (size_t)(n0 + srow) * 512 + kn + sc8 * 8,          bbf, bv0);
            ld4(Bp, (size_t)(n0 + srow) * 512 + kn + sc8 * 8 + 4,      bbf, bv0 + 4);
            ld4(Bp, (size_t)(n0 + srow + 32) * 512 + kn + sc8 * 8,     bbf, bv1);
            ld4(Bp, (size_t)(n0 + srow + 32) * 512 + kn + sc8 * 8 + 4, bbf, bv1 + 4);
        }
        for (int p = 0; p < npass; p++) {
            const int Ab = (p == 1 || p == 3) ? ALo : AHo;
            const int Bb = (p >= 2) ? BLo : BHo;
#pragma unroll
            for (int kk = 0; kk < 2; kk++) {
                bf16x8 af, bfr[2];
                af = *reinterpret_cast<const bf16x8*>(&lds[Ab + aoff[kk]]);
#pragma unroll
                for (int ni = 0; ni < 2; ni++)
                    bfr[ni] = *reinterpret_cast<const bf16x8*>(&lds[Bb + boff[ni][kk]]);
#pragma unroll
                for (int ni = 0; ni < 2; ni++)
                    acc[ni] = __builtin_amdgcn_mfma_f32_16x16x32_bf16(
                        af, bfr[ni], acc[ni], 0, 0, 0);
            }
        }
    }

    {
        int mbase = m0 + wm * 16 + (lane >> 4) * 4;
#pragma unroll
        for (int ni = 0; ni < 2; ni++) {
            int n = n0 + wn * 32 + ni * 16 + (lane & 15);
            if (epi == 0) {
#pragma unroll
                for (int r = 0; r < 4; r++) {
                    float v = acc[ni][r];
                    Cp[(size_t)(mbase + r) * N + n] = v;
                    if (Hout) {
                        unsigned short hb = f2bf(v);
                        unsigned short lb = f2bf(v - bf2f(hb));
                        size_t ho = (size_t)(hrow0 + mbase + r) * N + n;
                        Hout[ho] = hb;
                        Lout[ho] = lb;
                    }
                }
            } else {
                float bo = bias ? ldg1(bias, n, flag) : 0.f;
#pragma unroll
                for (int r = 0; r < 4; r++) {
                    float v = acc[ni][r] + bo;
                    size_t off = (size_t)(mbase + r) * N + n;
                    if (flag) ((unsigned short*)O)[off] = f2bf(v);
                    else      ((float*)O)[off] = v;
                }
            }
        }
    }
}

// ---------------------------------------------------------------------------
// Merged scores+qh GEMM on PRE-SPLIT bf16 inputs, 3-pass split-MFMA.
// A = Xh/Xl [4096][320]; B = Bh/Bl [1536][320] (rows 0-1023 = KW, 1024+ = M).
// Tile BM=128, BN=64, K-tile 64 (5 over K=320), 4 waves (2Mx2N), wave=64x32.
// LDS 48 KB; grid (24,32)=768 = 3/CU. Staging via global_load_lds width-16:
// linear LDS dest + inverse-swizzled per-lane global source.
// (Kept as a SEPARATE launch: merging with kv cost ~12us — the merged kernel
// forces 48KB LDS + max-regs on the light kv blocks. Round-8 lesson.)
// ---------------------------------------------------------------------------
__global__ __launch_bounds__(256) void gemm_scqh(
    const unsigned short* __restrict__ Xh, const unsigned short* __restrict__ Xl,
    const unsigned short* __restrict__ Bh, const unsigned short* __restrict__ Bl,
    float* __restrict__ Sc, float* __restrict__ qh)
{
    __shared__ __align__(16) short lds[24576];
    const int AHo = 0, ALo = 8192, BHo = 16384, BLo = 20480;  // short units
    const int t = threadIdx.x;
    const int m0 = blockIdx.y * 128, n0 = blockIdx.x * 64;
    const int lane = t & 63, wv = t >> 6;
    const int wm = wv >> 1, wn = wv & 1;
    const int lr = lane >> 3;      // row within 8-row staging issue
    const int lc = lane & 7;       // chunk within row

    int aoff[4][2], boff[2][2];
#pragma unroll
    for (int mi = 0; mi < 4; mi++)
#pragma unroll
        for (int kk = 0; kk < 2; kk++) {
            int ra = wm * 64 + mi * 16 + (lane & 15);
            int ca = kk * 4 + (lane >> 4);
            aoff[mi][kk] = ra * 64 + ((ca ^ (ra & 7)) << 3);
        }
#pragma unroll
    for (int ni = 0; ni < 2; ni++)
#pragma unroll
        for (int kk = 0; kk < 2; kk++) {
            int rb = wn * 32 + ni * 16 + (lane & 15);
            int cb = kk * 4 + (lane >> 4);
            boff[ni][kk] = rb * 64 + ((cb ^ (rb & 7)) << 3);
        }

    f32x4 acc[4][2];
#pragma unroll
    for (int mi = 0; mi < 4; mi++)
#pragma unroll
        for (int ni = 0; ni < 2; ni++)
            acc[mi][ni] = (f32x4){0.f, 0.f, 0.f, 0.f};

    char* smem = (char*)lds;

    for (int ks = 0; ks < 5; ks++) {
        const int kb = ks * 64;
        __syncthreads();  // prev compute done reading LDS
        // ---- stage A (Ah, Al): wave wv covers rows [wv*32, wv*32+32)
#pragma unroll
        for (int i = 0; i < 4; i++) {
            int r0 = wv * 32 + i * 8;          // wave-uniform local row base
            int r  = r0 + lr;                   // this lane's local row
            int sc = lc ^ (r & 7);              // inverse-swizzled source chunk
            size_t go = (size_t)(m0 + r) * 320 + kb + sc * 8;
            gload16(Xh + go, smem + (AHo << 1) + r0 * 128);
            gload16(Xl + go, smem + (ALo << 1) + r0 * 128);
        }
        // ---- stage B (Bh, Bl): wave wv covers rows [wv*16, wv*16+16)
#pragma unroll
        for (int i = 0; i < 2; i++) {
            int r0 = wv * 16 + i * 8;
            int r  = r0 + lr;
            int sc = lc ^ (r & 7);
            size_t go = (size_t)(n0 + r) * 320 + kb + sc * 8;
            gload16(Bh + go, smem + (BHo << 1) + r0 * 128);
            gload16(Bl + go, smem + (BLo << 1) + r0 * 128);
        }
        __syncthreads();  // drains vmcnt -> tiles ready
#pragma unroll
        for (int p = 0; p < 3; p++) {
            const int Ab = (p == 1) ? ALo : AHo;
            const int Bb = (p == 2) ? BLo : BHo;
#pragma unroll
            for (int kk = 0; kk < 2; kk++) {
                bf16x8 af[4], bfr[2];
#pragma unroll
                for (int mi = 0; mi < 4; mi++)
                    af[mi] = *reinterpret_cast<const bf16x8*>(&lds[Ab + aoff[mi][kk]]);
#pragma unroll
                for (int ni = 0; ni < 2; ni++)
                    bfr[ni] = *reinterpret_cast<const bf16x8*>(&lds[Bb + boff[ni][kk]]);
#pragma unroll
                for (int mi = 0; mi < 4; mi++)
#pragma unroll
                    for (int ni = 0; ni < 2; ni++)
                        acc[mi][ni] = __builtin_amdgcn_mfma_f32_16x16x32_bf16(
                            af[mi], bfr[ni], acc[mi][ni], 0, 0, 0);
            }
        }
    }

#pragma unroll
    for (int mi = 0; mi < 4; mi++) {
        int mbase = m0 + wm * 64 + mi * 16 + (lane >> 4) * 4;
#pragma unroll
        for (int ni = 0; ni < 2; ni++) {
            int n = n0 + wn * 32 + ni * 16 + (lane & 15);
#pragma unroll
            for (int r = 0; r < 4; r++) {
                float v = acc[mi][ni][r];
                int m = mbase + r;
                if (n0 < 1024) Sc[(size_t)m * 1024 + n] = v;
                else           qh[(size_t)m * 512 + (n - 1024)] = v;
            }
        }
    }
}

// ---------------------------------------------------------------------------
// Top-32 select, one wave per row. Binary search seeded with [rowmin,
// rowmax+1] (same invariant, same selection, ~40% fewer iterations).
// Fallback re-score: fp32 KWf (4-pass-MFMA accurate) with fp64 dot.
// ---------------------------------------------------------------------------
__global__ __launch_bounds__(256) void topk_select(
    const float* __restrict__ Sc, const void* __restrict__ X,
    const void* __restrict__ gdet, const float* __restrict__ KWf,
    int* __restrict__ idx)
{
    __shared__ unsigned int srow[4][1024];
    __shared__ unsigned int scv[4][64];
    __shared__ int          sci[4][64];
    const int bf = detect_bf(gdet);
    const int w = threadIdx.x >> 6, lane = threadIdx.x & 63;
    const int row = blockIdx.x * 4 + w;
    const float* S = Sc + (size_t)row * 1024;

    unsigned int mn = 0xFFFFFFFFu, mx = 0u;
#pragma unroll
    for (int q = 0; q < 4; q++) {
        float4 v = *reinterpret_cast<const float4*>(&S[lane * 4 + q * 256]);
        uint4 k = make_uint4(fkey(v.x), fkey(v.y), fkey(v.z), fkey(v.w));
        *reinterpret_cast<uint4*>(&srow[w][lane * 4 + q * 256]) = k;
        mn = min(mn, min(min(k.x, k.y), min(k.z, k.w)));
        mx = max(mx, max(max(k.x, k.y), max(k.z, k.w)));
    }
    scv[w][lane] = 0u;
    sci[w][lane] = 0x7FFFFFFF;
#pragma unroll
    for (int o = 1; o < 64; o <<= 1) {
        mn = min(mn, __shfl_xor(mn, o, 64));
        mx = max(mx, __shfl_xor(mx, o, 64));
    }
    __syncthreads();

    unsigned int lo = mn;
    unsigned int hi = (mx == 0xFFFFFFFFu) ? 0xFFFFFFFFu : mx + 1u;
    int cnt_lo = 1024;
    while (cnt_lo > 48 && hi - lo > 1u) {
        unsigned int mid = lo + ((hi - lo) >> 1);
        int c = 0;
#pragma unroll
        for (int q = 0; q < 4; q++) {
            uint4 k = *reinterpret_cast<const uint4*>(&srow[w][lane * 4 + q * 256]);
            c += (k.x >= mid) + (k.y >= mid) + (k.z >= mid) + (k.w >= mid);
        }
#pragma unroll
        for (int o = 1; o < 64; o <<= 1) c += __shfl_xor(c, o, 64);
        if (c >= 33) { lo = mid; cnt_lo = c; }
        else hi = mid;
    }
    const unsigned int T = lo;

    int cl = 0;
#pragma unroll
    for (int q = 0; q < 4; q++) {
        uint4 k = *reinterpret_cast<const uint4*>(&srow[w][lane * 4 + q * 256]);
        cl += (k.x >= T) + (k.y >= T) + (k.z >= T) + (k.w >= T);
    }
    int inc = cl;
#pragma unroll
    for (int o = 1; o < 64; o <<= 1) {
        int y = __shfl_up(inc, o, 64);
        if (lane >= o) inc += y;
    }
    int pos = inc - cl;
#pragma unroll
    for (int q = 0; q < 4; q++) {
        uint4 k = *reinterpret_cast<const uint4*>(&srow[w][lane * 4 + q * 256]);
        int base = lane * 4 + q * 256;
        if (k.x >= T && pos < 64) { scv[w][pos] = k.x; sci[w][pos] = base + 0; pos++; }
        if (k.y >= T && pos < 64) { scv[w][pos] = k.y; sci[w][pos] = base + 1; pos++; }
        if (k.z >= T && pos < 64) { scv[w][pos] = k.z; sci[w][pos] = base + 2; pos++; }
        if (k.w >= T && pos < 64) { scv[w][pos] = k.w; sci[w][pos] = base + 3; pos++; }
    }
    __syncthreads();
    unsigned int cv = scv[w][lane];
    int          ci = sci[w][lane];
#pragma unroll
    for (int k = 2; k <= 64; k <<= 1) {
#pragma unroll
        for (int jj = k >> 1; jj > 0; jj >>= 1) {
            unsigned int ov = __shfl_xor(cv, jj, 64);
            int          oi = __shfl_xor(ci, jj, 64);
            bool up = ((lane & k) == 0);
            bool takemax = (((lane & jj) == 0) == up);
            bool othergreater = (ov > cv) || (ov == cv && oi < ci);
            if (takemax == othergreater) { cv = ov; ci = oi; }
        }
    }
    float v31 = funkey(__shfl(cv, 31, 64));
    float v32 = funkey(__shfl(cv, 32, 64));
    if (v31 - v32 > 2.5e-4f) {
        if (lane < 32) idx[(size_t)row * 32 + lane] = ci;
        return;
    }
    size_t xb = (size_t)row * 320;
    bool active = (lane < 48) && (ci != 0x7FFFFFFF);
    int cidx = active ? ci : 0x7FFFFFFF;
    const float* kr = KWf + (size_t)(active ? ci : 0) * 320;
    double s = 0.0;
#pragma unroll 4
    for (int d = 0; d < 320; d++) {
        float xd = ldg1(X, xb + d, bf);
        s += (double)xd * (double)kr[d];
    }
    if (!active) s = -1.0e300;
#pragma unroll
    for (int k = 2; k <= 64; k <<= 1) {
#pragma unroll
        for (int jj = k >> 1; jj > 0; jj >>= 1) {
            double os = __shfl_xor(s, jj, 64);
            int    oi = __shfl_xor(cidx, jj, 64);
            bool up = ((lane & k) == 0);
            bool takemax = (((lane & jj) == 0) == up);
            bool og = (os > s) || (os == s && oi < cidx);
            if (takemax == og) { s = os; cidx = oi; }
        }
    }
    if (lane < 32) idx[(size_t)row * 32 + lane] = cidx;
}

// ---------------------------------------------------------------------------
// Fused gather + 8-head attention per row. QK: one wave per slot-row,
// coalesced full-line reads + 8-lane-group shuffle reduce. PV: float2 cols.
// ---------------------------------------------------------------------------
__global__ __launch_bounds__(256) void attn_kernel(
    const float* __restrict__ qh, const float* __restrict__ Kp,
    const float* __restrict__ Vp, const int* __restrict__ idx,
    float* __restrict__ ctx)
{
    __shared__ float sq[512];
    __shared__ int   sidx[32];
    __shared__ float sl[8][32];
    __shared__ float sw[8][32];
    int row = blockIdx.x, t = threadIdx.x;
    int w = t >> 6, l = t & 63;
    if (t < 128)
        *reinterpret_cast<float4*>(&sq[t * 4]) =
            *reinterpret_cast<const float4*>(&qh[(size_t)row * 512 + t * 4]);
    if (t < 32) {
        int v = idx[(size_t)row * 32 + t];
        sidx[t] = (v < 0) ? 0 : (v > 1023 ? 1023 : v);
    }
    __syncthreads();

    float4 q0 = *reinterpret_cast<const float4*>(&sq[l * 8]);
    float4 q1 = *reinterpret_cast<const float4*>(&sq[l * 8 + 4]);
    int h = l >> 3;
#pragma unroll
    for (int i = 0; i < 8; i++) {
        int s = w * 8 + i;
        const float* kp = Kp + (size_t)sidx[s] * 512 + l * 8;
        float4 k0 = *reinterpret_cast<const float4*>(kp);
        float4 k1 = *reinterpret_cast<const float4*>(kp + 4);
        float p = q0.x * k0.x + q0.y * k0.y + q0.z * k0.z + q0.w * k0.w
                + q1.x * k1.x + q1.y * k1.y + q1.z * k1.z + q1.w * k1.w;
        p += __shfl_xor(p, 1, 64);
        p += __shfl_xor(p, 2, 64);
        p += __shfl_xor(p, 4, 64);
        if ((l & 7) == 0) sl[h][s] = p * 0.125f;
    }
    __syncthreads();

    int hh = t >> 5, kk = t & 31;
    float logit = sl[hh][kk];
    float m = -1e30f;
#pragma unroll
    for (int i = 0; i < 32; i++) m = fmaxf(m, sl[hh][i]);
    float ssum = 0.f;
#pragma unroll
    for (int i = 0; i < 32; i++) ssum += __expf(sl[hh][i] - m);
    sw[hh][kk] = __expf(logit - m) / ssum;
    __syncthreads();

    int c = t * 2, hc = c >> 6;
    float ax = 0.f, ay = 0.f;
#pragma unroll
    for (int k2 = 0; k2 < 32; k2++) {
        float2 vv = *reinterpret_cast<const float2*>(&Vp[(size_t)sidx[k2] * 512 + c]);
        float wgt = sw[hc][k2];
        ax += wgt * vv.x; ay += wgt * vv.y;
    }
    *reinterpret_cast<float2*>(&ctx[(size_t)row * 512 + c]) = make_float2(ax, ay);
}

extern "C" void kernel_launch(void* const* d_in, const int* in_sizes, int n_in,
                              void* d_out, int out_size, void* d_ws, size_t ws_size,
                              hipStream_t stream)
{
    const void* X    = d_in[0];
    const void* Wqp  = d_in[1];
    const void* keys = d_in[2];
    const void* vals = d_in[3];
    const void* Wq   = d_in[4];
    const void* Wk   = d_in[5];
    const void* Wv   = d_in[6];
    const void* Wo   = d_in[7];
    const void* ln_g = d_in[8];
    const void* ln_b = d_in[9];
    const void* Wout = d_in[10];
    const void* bout = d_in[11];

    // ---- workspace (float units; ~43 MiB of the 256 MiB pool) ----
    float* ws = (float*)d_ws;
    float*  Sc     = ws;                       // 4096x1024 fp32
    float*  co     = ws;                       // reuses Sc region after topk
    float*  Yreg   = ws + 2097152;             // ctx (post-topk)
    float*  qh     = ws + 4194304;             // 4096x512
    float*  Mf     = ws + 6291456;             // 512*320 (Kp region; Mf dead after prep)
    float*  Kp     = ws + 6291456;
    float*  KWf    = ws + 6815744;             // 1024*320 — read by topk; no alias!
    float*  WqpT   = ws + 7340032;             // 320*512 fp32
    int*    idx    = (int*)(ws + 7995392);
    float*  inv_kf = ws + 8128512;
    float*  inv_vf = ws + 8129536;
    unsigned short* Xh  = (unsigned short*)(ws + 8388608);   // 4096x320 bf16
    unsigned short* Xl  = (unsigned short*)(ws + 9043968);
    unsigned short* Bh  = (unsigned short*)(ws + 9699328);   // 1536x320 bf16
    unsigned short* Bl  = (unsigned short*)(ws + 9945088);
    float*  Vp     = ws + 10190848;            // 1024x512 — dedicated
    float*  ctx    = Yreg;

    // fused norms + WqpT transpose + X presplit (2048 + 160 + 640 blocks)
    prep_fused<<<2848, 256, 0, stream>>>(
        keys, vals, Wqp, X, ln_g, inv_kf, inv_vf, WqpT, Xh, Xl);
    // merged KWf (rowscale(keys)@WqpT^T, 4-pass: fp32-accurate for tie-break)
    // + Mf (Wq@WqpT^T); also emits bf16 h/l into stacked Bh/Bl [1536][320].
    mfma_abt<<<dim3(5, 48), 256, 0, stream>>>(
        keys, WqpT, inv_kf, KWf, Wq, WqpT, nullptr, Mf, 32,
        nullptr, nullptr, nullptr, nullptr, nullptr,
        Bh, Bl, 0, 1024,
        320, 1, 1, 0, 0, 4, ln_g);
    gemm_scqh<<<dim3(24, 32), 256, 0, stream>>>(Xh, Xl, Bh, Bl, Sc, qh);
    topk_select<<<1024, 256, 0, stream>>>(Sc, X, ln_g, KWf, idx);
    // Kp/Vp: merged, rowscale, split-MFMA (3-pass), 512 blocks = 2/CU
    mfma_abt<<<dim3(8, 64), 256, 0, stream>>>(
        keys, Wk, inv_kf, Kp, vals, Wv, inv_vf, Vp, 32,
        nullptr, nullptr, nullptr, nullptr, nullptr,
        nullptr, nullptr, 0, 0,
        512, 1, 1, 1, 0, 3, ln_g);
    attn_kernel<<<4096, 256, 0, stream>>>(qh, Kp, Vp, idx, ctx);
    // ctx @ Wo^T -> co (split-MFMA, 3-pass), 1024 blocks = 4/CU
    mfma_abt<<<dim3(8, 128), 256, 0, stream>>>(
        ctx, Wo, nullptr, co, nullptr, nullptr, nullptr, nullptr, 0,
        nullptr, nullptr, nullptr, nullptr, nullptr,
        nullptr, nullptr, 0, 0,
        512, 0, 0, 1, 0, 3, ln_g);
    // out = (LN(co)*g+b) @ Wout^T + bout; LN stats computed in-kernel
    // (stats=nullptr -> fp64 pre-pass over co), 640 blocks
    mfma_abt<<<dim3(5, 128), 256, 0, stream>>>(
        co, Wout, nullptr, nullptr, nullptr, nullptr, nullptr, nullptr, 0,
        nullptr, ln_g, ln_b, bout, d_out,
        nullptr, nullptr, 0, 0,
        320, 2, 0, 1, 1, 3, ln_g);
}